// Round 3
// baseline (5509.528 us; speedup 1.0000x reference)
//
#include <hip/hip_runtime.h>
#include <math.h>

#define BB 32
#define TT 24
#define NN 256
#define FF 16
#define HH 128
#define G4 512  // 4*H

typedef _Float16 half8 __attribute__((ext_vector_type(8)));
typedef _Float16 half4 __attribute__((ext_vector_type(4)));
typedef float f32x4 __attribute__((ext_vector_type(4)));

__device__ __forceinline__ float sigf(float x) { return 1.f / (1.f + __expf(-x)); }
__device__ __forceinline__ float tanhfast(float x) { return 1.f - 2.f / (__expf(2.f * x) + 1.f); }

// fp32 -> (hi, lo) fp16 split: v ~= hi + lo, residual ~2^-22 relative.
__device__ __forceinline__ void split8(const float* v, half8& hi, half8& lo) {
#pragma unroll
  for (int i = 0; i < 8; ++i) {
    const _Float16 h = (_Float16)v[i];
    hi[i] = h;
    lo[i] = (_Float16)(v[i] - (float)h);
  }
}

// ---------------------------------------------------------------------------
// K0a: pre-split+swizzle gcn_W into B-frag tiles.
// Wfrag[kc(5)][ct(32)][lane][8]: element W_op[k][n]:
//   kc<4 : gcnW[16 + kc*32 + k][ct*16 + n]   (h part, rows 16..143)
//   kc==4: k<16 ? gcnW[k][ct*16+n] : 0       (x part zero-padded to K=32)
// with k = (lane>>4)*8 + j, n = lane&15.
// ---------------------------------------------------------------------------
__global__ __launch_bounds__(64) void k0_wswz(const float* __restrict__ gcnW,
                                              _Float16* __restrict__ WfH,
                                              _Float16* __restrict__ WfL) {
  const int bid = blockIdx.x;  // kc*32 + ct, 0..159
  const int kc = bid >> 5, ct = bid & 31;
  const int l = threadIdx.x, quad = l >> 4, lo16 = l & 15;
  float v[8];
#pragma unroll
  for (int j = 0; j < 8; ++j) {
    const int k = quad * 8 + j;
    float val = 0.f;
    if (kc < 4) val = gcnW[(size_t)(16 + kc * 32 + k) * G4 + ct * 16 + lo16];
    else if (k < 16) val = gcnW[(size_t)k * G4 + ct * 16 + lo16];
    v[j] = val;
  }
  half8 hi, lo;
  split8(v, hi, lo);
  const size_t off = (size_t)bid * 512 + l * 8;
  *(half8*)&WfH[off] = hi;
  *(half8*)&WfL[off] = lo;
}

// ---------------------------------------------------------------------------
// K0b: pre-split+swizzle adjacency (adj[:, T-1]) into A-frag tiles.
// Afrag[b][nt16(16)][kc(8)][lane][8]: element adj[b][T-1][m][k],
//   m = nt16*16 + (lane&15), k = kc*32 + (lane>>4)*8 + j.
// ---------------------------------------------------------------------------
__global__ __launch_bounds__(64) void k0_aswz(const float* __restrict__ adj,
                                              _Float16* __restrict__ AfH,
                                              _Float16* __restrict__ AfL) {
  const int nt16 = blockIdx.x >> 3, kc = blockIdx.x & 7;
  const int b = blockIdx.y;
  const int l = threadIdx.x, quad = l >> 4, lo16 = l & 15;
  const float* src =
      adj + (((size_t)(b * TT + TT - 1)) * NN + nt16 * 16 + lo16) * NN + kc * 32 + quad * 8;
  const float4 v0 = *(const float4*)src;
  const float4 v1 = *(const float4*)(src + 4);
  float v[8] = {v0.x, v0.y, v0.z, v0.w, v1.x, v1.y, v1.z, v1.w};
  half8 hi, lo;
  split8(v, hi, lo);
  const size_t off = (((size_t)b * 16 + nt16) * 8 + kc) * 512 + l * 8;
  *(half8*)&AfH[off] = hi;
  *(half8*)&AfL[off] = lo;
}

// ---------------------------------------------------------------------------
// K1: Ax[b,t,n,f] = sum_j A[b,n,j] * x[b,t,j,f]   (fp32, parallel over b,t)
// ---------------------------------------------------------------------------
__global__ __launch_bounds__(256) void k1_ax(const float* __restrict__ adj,
                                             const float* __restrict__ x,
                                             float* __restrict__ Ax) {
  const int bt = blockIdx.x;
  const int b = bt / TT;
  const float* Abase = adj + ((size_t)(b * TT + (TT - 1)) * NN) * NN;
  const float* xbase = x + (size_t)bt * NN * FF;

  __shared__ float x_s[NN * FF];
  __shared__ float A_s[64 * 65];

  for (int i4 = threadIdx.x; i4 < (NN * FF) / 4; i4 += 256) {
    ((float4*)x_s)[i4] = ((const float4*)xbase)[i4];
  }
  const int rg = threadIdx.x >> 2;
  const int fg = threadIdx.x & 3;

  for (int rt = 0; rt < 4; ++rt) {
    float4 acc = make_float4(0.f, 0.f, 0.f, 0.f);
    for (int jc = 0; jc < 4; ++jc) {
      __syncthreads();
      for (int i = threadIdx.x; i < 64 * 64; i += 256) {
        const int r = i >> 6, j = i & 63;
        A_s[r * 65 + j] = Abase[(size_t)(rt * 64 + r) * NN + jc * 64 + j];
      }
      __syncthreads();
#pragma unroll 8
      for (int j = 0; j < 64; ++j) {
        const float a = A_s[rg * 65 + j];
        const float4 xv = *(const float4*)&x_s[(jc * 64 + j) * FF + fg * 4];
        acc.x += a * xv.x;
        acc.y += a * xv.y;
        acc.z += a * xv.z;
        acc.w += a * xv.w;
      }
    }
    *(float4*)&Ax[((size_t)bt * NN + rt * 64 + rg) * FF + fg * 4] = acc;
  }
}

// ---------------------------------------------------------------------------
// K2: one block per b, 1024 threads (16 waves), all TT steps in-block.
// No cross-block communication at all: h lives in LDS as split-fp16 frag
// tiles hF[kc(8)][ct(8)][512], c lives in registers (32/thread).
// Per step, 8 chunks of 32 nodes:
//   phase A: wave w (rt=w>>3, ct=w&7) computes one 16x16 tile of
//     Ah(32x128) = A(32x256)@h — A-frags from global (L1/L2-hit),
//     h-frags from LDS. C-write into region (stride 164) cols 0..127;
//     Ax[t] staged into cols 128..143; cols 144..159 are zero pad.
//   phase B: wave w computes gate tiles ct = g*8+hc (g=0..3, hc=w&7) for
//     row tile rt=w>>3 -> each lane holds i,f,g,o of one hidden column ->
//     LSTM pointwise fully in registers; h(t+1) kept in regs.
//   end of step: h(t+1) regs -> split fp16 -> hF via one ds_write_b64 per
//     plane per chunk (4 values land in 4 consecutive frag slots).
// LDS: hFH 64K + hFL 64K + region 20.5K = 148.5 KB. Grid 32 -> 4 blocks/XCD.
// ---------------------------------------------------------------------------
__global__ __launch_bounds__(1024, 4) void k2_b(
    const _Float16* __restrict__ AfH, const _Float16* __restrict__ AfL,
    const _Float16* __restrict__ WfH, const _Float16* __restrict__ WfL,
    const float* __restrict__ Ax, const float* __restrict__ gcnb,
    float* __restrict__ h32) {
  const int b = blockIdx.x;
  const int tid = threadIdx.x;
  const int w = tid >> 6, l = tid & 63, quad = l >> 4, lo16 = l & 15;
  const int rt = w >> 3;  // row-tile within chunk (0/1)
  const int hc = w & 7;   // hidden-col tile (phase A ct; phase B gate tiles g*8+hc)

  __shared__ _Float16 hFH[8 * 8 * 512];
  __shared__ _Float16 hFL[8 * 8 * 512];
  __shared__ float region[32 * 164];  // Ah (0..127) | Ax (128..143) | 0 (144..159)

  // ---- init: hF = 0 (h(-1)=0), zero pad cols 144..159 ----
  {
    const half8 z = {};
    for (int i = tid; i < 4096; i += 1024) {
      *(half8*)&hFH[i * 8] = z;
      *(half8*)&hFL[i * 8] = z;
    }
    if (tid < 512) region[(tid >> 4) * 164 + 144 + (tid & 15)] = 0.f;
  }

  // bias registers: this thread's hidden col = hc*16+lo16, gates i,f,g,o
  float bi[4];
#pragma unroll
  for (int g = 0; g < 4; ++g) bi[g] = gcnb[g * HH + hc * 16 + lo16];

  float c_r[32];  // cell state: (chunk rc, r) -> node rc*32 + rt*16 + quad*4 + r
#pragma unroll
  for (int i = 0; i < 32; ++i) c_r[i] = 0.f;

  __syncthreads();  // hF init visible

  for (int t = 0; t < TT; ++t) {
    float hreg[32];  // h(t+1) values, written to hF at end of step

#pragma unroll
    for (int rc = 0; rc < 8; ++rc) {
      // ---- phase A: one 16x16 tile per wave ----
      f32x4 accA = (f32x4){0.f, 0.f, 0.f, 0.f};
      const size_t abase = (((size_t)b * 16 + 2 * rc + rt) * 8) * 512 + l * 8;
      for (int kc = 0; kc < 8; ++kc) {
        const half8 aH = *(const half8*)&AfH[abase + (size_t)kc * 512];
        const half8 aL = *(const half8*)&AfL[abase + (size_t)kc * 512];
        const half8 bH = *(const half8*)&hFH[(kc * 8 + hc) * 512 + l * 8];
        const half8 bL = *(const half8*)&hFL[(kc * 8 + hc) * 512 + l * 8];
        accA = __builtin_amdgcn_mfma_f32_16x16x32_f16(aL, bH, accA, 0, 0, 0);
        accA = __builtin_amdgcn_mfma_f32_16x16x32_f16(aH, bL, accA, 0, 0, 0);
        accA = __builtin_amdgcn_mfma_f32_16x16x32_f16(aH, bH, accA, 0, 0, 0);
      }
      // stage Ax[t] chunk -> region cols 128..143 (prev phase B done: B2 sync)
      if (tid < 512) {
        const int r = tid >> 4, f = tid & 15;
        region[r * 164 + 128 + f] =
            Ax[(((size_t)(b * TT + t)) * NN + rc * 32 + r) * FF + f];
      }
      // C-write Ah (col=lane&15, row=quad*4+reg)
#pragma unroll
      for (int r = 0; r < 4; ++r)
        region[(rt * 16 + quad * 4 + r) * 164 + hc * 16 + lo16] = accA[r];
      __syncthreads();  // B1: Ah + Ax staged

      // ---- phase B: 4 gate tiles (i,f,g,o of hidden tile hc), row tile rt ----
      f32x4 acc[4];
#pragma unroll
      for (int g = 0; g < 4; ++g) acc[g] = (f32x4){0.f, 0.f, 0.f, 0.f};

      for (int kc = 0; kc < 5; ++kc) {
        const float* src = &region[(rt * 16 + lo16) * 164 + kc * 32 + quad * 8];
        const float4 v0 = *(const float4*)src;
        const float4 v1 = *(const float4*)(src + 4);
        float av[8] = {v0.x, v0.y, v0.z, v0.w, v1.x, v1.y, v1.z, v1.w};
        half8 pH, pL;
        split8(av, pH, pL);
#pragma unroll
        for (int g = 0; g < 4; ++g) {
          const size_t woff = ((size_t)(kc * 32 + g * 8 + hc)) * 512 + l * 8;
          const half8 wH = *(const half8*)&WfH[woff];
          const half8 wL = *(const half8*)&WfL[woff];
          acc[g] = __builtin_amdgcn_mfma_f32_16x16x32_f16(pL, wH, acc[g], 0, 0, 0);
          acc[g] = __builtin_amdgcn_mfma_f32_16x16x32_f16(pH, wL, acc[g], 0, 0, 0);
          acc[g] = __builtin_amdgcn_mfma_f32_16x16x32_f16(pH, wH, acc[g], 0, 0, 0);
        }
      }

      // ---- LSTM pointwise, fully in registers on C layout ----
#pragma unroll
      for (int r = 0; r < 4; ++r) {
        const float iv = sigf(acc[0][r] + bi[0]);
        const float fv = sigf(acc[1][r] + bi[1]);
        const float gv = tanhfast(acc[2][r] + bi[2]);
        const float ov = sigf(acc[3][r] + bi[3]);
        const float cnew = fv * c_r[rc * 4 + r] + iv * gv;
        c_r[rc * 4 + r] = cnew;
        const float hv = ov * tanhfast(cnew);
        hreg[rc * 4 + r] = hv;
        if (t == TT - 1 && rc == 0) {
          const int node = rt * 16 + quad * 4 + r;
          h32[((size_t)b * 32 + node) * HH + hc * 16 + lo16] = hv;
        }
      }
      __syncthreads();  // B2: region reads done (next chunk overwrites)
    }

    // ---- end of step: h(t+1) regs -> hF split-fp16 frags ----
    if (t != TT - 1) {
      // thread's 4 chunk-values sit in 4 consecutive j-slots of one frag row:
      // node = rc*32 + rt*16 + quad*4 + r -> kc=rc, lp = (rt*2+(quad>>1))*16+lo16,
      // j = (quad&1)*4 + r.
      const int lp = (rt * 2 + (quad >> 1)) * 16 + lo16;
      const int j0 = (quad & 1) * 4;
#pragma unroll
      for (int rc = 0; rc < 8; ++rc) {
        half4 h4, l4;
#pragma unroll
        for (int r = 0; r < 4; ++r) {
          const float v = hreg[rc * 4 + r];
          const _Float16 hh = (_Float16)v;
          h4[r] = hh;
          l4[r] = (_Float16)(v - (float)hh);
        }
        const size_t hoff = ((size_t)rc * 8 + hc) * 512 + lp * 8 + j0;
        *(half4*)&hFH[hoff] = h4;
        *(half4*)&hFL[hoff] = l4;
      }
      __syncthreads();  // hF(t+1) ready for next step's phase A
    }
  }
}

// ---------------------------------------------------------------------------
// Tail: GRU over t + fc5/fc2/fc3/fc4. grid = B, 384 threads.
// h32 layout: [b][node 0..31][128] (only node tile 0 is stored; tsi=5 < 32).
// ---------------------------------------------------------------------------
__global__ __launch_bounds__(384) void k_tail(
    const float* __restrict__ x, const float* __restrict__ h32,
    const int* __restrict__ tsi_p, const float* __restrict__ gruWih,
    const float* __restrict__ gruWhh, const float* __restrict__ gru_bih,
    const float* __restrict__ gru_bhh, const float* __restrict__ fc2W,
    const float* __restrict__ fc2b, const float* __restrict__ fc3W,
    const float* __restrict__ fc3b, const float* __restrict__ fc4W,
    const float* __restrict__ fc4b, const float* __restrict__ fc5W,
    const float* __restrict__ fc5b, float* __restrict__ out) {
  const int b = blockIdx.x;
  const int m = threadIdx.x;
  const int tsi = tsi_p[0];

  __shared__ float h_s[HH];
  __shared__ float xts[TT * FF];
  __shared__ float sum_s[384];
  __shared__ float gh_s[384];
  __shared__ float hc_s[2 * HH];
  __shared__ float xr_s[HH];
  __shared__ float f2_s[HH];
  __shared__ float f3_s[64];

  float4 whh[32];
#pragma unroll
  for (int q = 0; q < 32; ++q) whh[q] = *(const float4*)&gruWhh[(size_t)m * HH + q * 4];
  float4 wih[4];
#pragma unroll
  for (int q = 0; q < 4; ++q) wih[q] = *(const float4*)&gruWih[(size_t)m * FF + q * 4];
  const float bih_r = gru_bih[m];
  const float bhh_r = gru_bhh[m];

  {
    const int t = m >> 4, f = m & 15;
    xts[m] = x[(((size_t)b * TT + t) * NN + tsi) * FF + f];
  }
  if (m < HH) h_s[m] = 0.f;
  __syncthreads();

  for (int t = 0; t < TT; ++t) {
    float gi = bih_r;
#pragma unroll
    for (int q = 0; q < 4; ++q) {
      const float4 xv = *(const float4*)&xts[t * FF + q * 4];
      gi += wih[q].x * xv.x + wih[q].y * xv.y + wih[q].z * xv.z + wih[q].w * xv.w;
    }
    float gh = bhh_r;
#pragma unroll
    for (int q = 0; q < 32; ++q) {
      const float4 hv = *(const float4*)&h_s[q * 4];
      gh += whh[q].x * hv.x + whh[q].y * hv.y + whh[q].z * hv.z + whh[q].w * hv.w;
    }
    sum_s[m] = gi + gh;
    gh_s[m] = gh;
    __syncthreads();
    float hnew = 0.f;
    if (m < HH) {
      const float r = sigf(sum_s[m]);
      const float z = sigf(sum_s[HH + m]);
      const float ghn = gh_s[2 * HH + m];
      const float nn = tanhfast(sum_s[2 * HH + m] - ghn + r * ghn);
      hnew = (1.f - z) * nn + z * h_s[m];
    }
    __syncthreads();
    if (m < HH) h_s[m] = hnew;
    __syncthreads();
  }

  if (m < HH) {
    hc_s[m] = h_s[m];
    xr_s[m] = fmaxf(h32[((size_t)b * 32 + tsi) * HH + m], 0.f);
  }
  __syncthreads();
  if (m < HH) {
    float v = fc5b[m];
    const float* wr = fc5W + (size_t)m * HH;
#pragma unroll 8
    for (int k = 0; k < HH; k += 4) {
      const float4 wv = *(const float4*)(wr + k);
      v += xr_s[k] * wv.x + xr_s[k + 1] * wv.y + xr_s[k + 2] * wv.z + xr_s[k + 3] * wv.w;
    }
    hc_s[HH + m] = v;
  }
  __syncthreads();
  if (m < HH) {
    float v = fc2b[m];
    const float* wr = fc2W + (size_t)m * 2 * HH;
#pragma unroll 8
    for (int k = 0; k < 2 * HH; k += 4) {
      const float4 wv = *(const float4*)(wr + k);
      v += hc_s[k] * wv.x + hc_s[k + 1] * wv.y + hc_s[k + 2] * wv.z + hc_s[k + 3] * wv.w;
    }
    f2_s[m] = fmaxf(v, 0.f);
  }
  __syncthreads();
  if (m < 64) {
    float v = fc3b[m];
    const float* wr = fc3W + (size_t)m * HH;
#pragma unroll 8
    for (int k = 0; k < HH; k += 4) {
      const float4 wv = *(const float4*)(wr + k);
      v += f2_s[k] * wv.x + f2_s[k + 1] * wv.y + f2_s[k + 2] * wv.z + f2_s[k + 3] * wv.w;
    }
    f3_s[m] = fmaxf(v, 0.f);
  }
  __syncthreads();
  if (m < 24) {
    float v = fc4b[m];
    const float* wr = fc4W + (size_t)m * 64;
#pragma unroll
    for (int k = 0; k < 64; k += 4) {
      const float4 wv = *(const float4*)(wr + k);
      v += f3_s[k] * wv.x + f3_s[k + 1] * wv.y + f3_s[k + 2] * wv.z + f3_s[k + 3] * wv.w;
    }
    out[b * 24 + m] = v;
  }
}

// ---------------------------------------------------------------------------
extern "C" void kernel_launch(void* const* d_in, const int* in_sizes, int n_in,
                              void* d_out, int out_size, void* d_ws, size_t ws_size,
                              hipStream_t stream) {
  const float* x = (const float*)d_in[0];
  const float* adj = (const float*)d_in[1];
  const int* tsi = (const int*)d_in[2];
  const float* gcnW = (const float*)d_in[3];
  const float* gcnb = (const float*)d_in[4];
  const float* gruWih = (const float*)d_in[5];
  const float* gruWhh = (const float*)d_in[6];
  const float* gru_bih = (const float*)d_in[7];
  const float* gru_bhh = (const float*)d_in[8];
  const float* fc2W = (const float*)d_in[9];
  const float* fc2b = (const float*)d_in[10];
  const float* fc3W = (const float*)d_in[11];
  const float* fc3b = (const float*)d_in[12];
  const float* fc4W = (const float*)d_in[13];
  const float* fc4b = (const float*)d_in[14];
  const float* fc5W = (const float*)d_in[15];
  const float* fc5b = (const float*)d_in[16];
  float* out = (float*)d_out;

  // ws layout (elements)
  float* Ax = (float*)d_ws;                           // 32*24*256*16 = 3,145,728 f
  float* h32 = Ax + 3145728;                          // 32*32*128   =   131,072 f
  _Float16* AfH = (_Float16*)(h32 + 131072);          // 32*16*8*512 = 2,097,152 h
  _Float16* AfL = AfH + 2097152;                      // 2,097,152 h
  _Float16* WfH = AfL + 2097152;                      // 5*32*512    =    81,920 h
  _Float16* WfL = WfH + 81920;                        // 81,920 h

  k0_wswz<<<dim3(160), 64, 0, stream>>>(gcnW, WfH, WfL);
  k0_aswz<<<dim3(128, BB), 64, 0, stream>>>(adj, AfH, AfL);
  k1_ax<<<dim3(BB * TT), 256, 0, stream>>>(adj, x, Ax);

  // one block per b; entire 24-step scan runs in-block (no cross-block sync)
  k2_b<<<dim3(BB), 1024, 0, stream>>>(AfH, AfL, WfH, WfL, Ax, gcnb, h32);

  k_tail<<<dim3(BB), 384, 0, stream>>>(x, h32, tsi, gruWih, gruWhh, gru_bih, gru_bhh, fc2W,
                                       fc2b, fc3W, fc3b, fc4W, fc4b, fc5W, fc5b, out);
}

// Round 4
// 5195.886 us; speedup vs baseline: 1.0604x; 1.0604x over previous
//
#include <hip/hip_runtime.h>
#include <math.h>

#define BB 32
#define TT 24
#define NN 256
#define FF 16
#define HH 128
#define G4 512  // 4*H

typedef _Float16 half8 __attribute__((ext_vector_type(8)));
typedef _Float16 half4 __attribute__((ext_vector_type(4)));
typedef float f32x4 __attribute__((ext_vector_type(4)));

__device__ __forceinline__ float sigf(float x) { return 1.f / (1.f + __expf(-x)); }
__device__ __forceinline__ float tanhfast(float x) { return 1.f - 2.f / (__expf(2.f * x) + 1.f); }

// fp32 -> (hi, lo) fp16 split: v ~= hi + lo, residual ~2^-22 relative.
__device__ __forceinline__ void split8(const float* v, half8& hi, half8& lo) {
#pragma unroll
  for (int i = 0; i < 8; ++i) {
    const _Float16 h = (_Float16)v[i];
    hi[i] = h;
    lo[i] = (_Float16)(v[i] - (float)h);
  }
}

// ---------------------------------------------------------------------------
// K0a: pre-split+swizzle gcn_W into B-frag tiles.
// Wfrag[kc(5)][ct(32)][lane][8]: element W_op[k][n]:
//   kc<4 : gcnW[16 + kc*32 + k][ct*16 + n]   (h part, rows 16..143)
//   kc==4: k<16 ? gcnW[k][ct*16+n] : 0       (x part zero-padded to K=32)
// with k = (lane>>4)*8 + j, n = lane&15.
// ---------------------------------------------------------------------------
__global__ __launch_bounds__(64) void k0_wswz(const float* __restrict__ gcnW,
                                              _Float16* __restrict__ WfH,
                                              _Float16* __restrict__ WfL) {
  const int bid = blockIdx.x;  // kc*32 + ct, 0..159
  const int kc = bid >> 5, ct = bid & 31;
  const int l = threadIdx.x, quad = l >> 4, lo16 = l & 15;
  float v[8];
#pragma unroll
  for (int j = 0; j < 8; ++j) {
    const int k = quad * 8 + j;
    float val = 0.f;
    if (kc < 4) val = gcnW[(size_t)(16 + kc * 32 + k) * G4 + ct * 16 + lo16];
    else if (k < 16) val = gcnW[(size_t)k * G4 + ct * 16 + lo16];
    v[j] = val;
  }
  half8 hi, lo;
  split8(v, hi, lo);
  const size_t off = (size_t)bid * 512 + l * 8;
  *(half8*)&WfH[off] = hi;
  *(half8*)&WfL[off] = lo;
}

// ---------------------------------------------------------------------------
// K0b: pre-split+swizzle adjacency (adj[:, T-1]) into A-frag tiles.
// Afrag[b][nt16(16)][kc(8)][lane][8]: element adj[b][T-1][m][k],
//   m = nt16*16 + (lane&15), k = kc*32 + (lane>>4)*8 + j.
// ---------------------------------------------------------------------------
__global__ __launch_bounds__(64) void k0_aswz(const float* __restrict__ adj,
                                              _Float16* __restrict__ AfH,
                                              _Float16* __restrict__ AfL) {
  const int nt16 = blockIdx.x >> 3, kc = blockIdx.x & 7;
  const int b = blockIdx.y;
  const int l = threadIdx.x, quad = l >> 4, lo16 = l & 15;
  const float* src =
      adj + (((size_t)(b * TT + TT - 1)) * NN + nt16 * 16 + lo16) * NN + kc * 32 + quad * 8;
  const float4 v0 = *(const float4*)src;
  const float4 v1 = *(const float4*)(src + 4);
  float v[8] = {v0.x, v0.y, v0.z, v0.w, v1.x, v1.y, v1.z, v1.w};
  half8 hi, lo;
  split8(v, hi, lo);
  const size_t off = (((size_t)b * 16 + nt16) * 8 + kc) * 512 + l * 8;
  *(half8*)&AfH[off] = hi;
  *(half8*)&AfL[off] = lo;
}

// ---------------------------------------------------------------------------
// K1: Ax[b,t,n,f] = sum_j A[b,n,j] * x[b,t,j,f]   (fp32, parallel over b,t)
// ---------------------------------------------------------------------------
__global__ __launch_bounds__(256) void k1_ax(const float* __restrict__ adj,
                                             const float* __restrict__ x,
                                             float* __restrict__ Ax) {
  const int bt = blockIdx.x;
  const int b = bt / TT;
  const float* Abase = adj + ((size_t)(b * TT + (TT - 1)) * NN) * NN;
  const float* xbase = x + (size_t)bt * NN * FF;

  __shared__ float x_s[NN * FF];
  __shared__ float A_s[64 * 65];

  for (int i4 = threadIdx.x; i4 < (NN * FF) / 4; i4 += 256) {
    ((float4*)x_s)[i4] = ((const float4*)xbase)[i4];
  }
  const int rg = threadIdx.x >> 2;
  const int fg = threadIdx.x & 3;

  for (int rt = 0; rt < 4; ++rt) {
    float4 acc = make_float4(0.f, 0.f, 0.f, 0.f);
    for (int jc = 0; jc < 4; ++jc) {
      __syncthreads();
      for (int i = threadIdx.x; i < 64 * 64; i += 256) {
        const int r = i >> 6, j = i & 63;
        A_s[r * 65 + j] = Abase[(size_t)(rt * 64 + r) * NN + jc * 64 + j];
      }
      __syncthreads();
#pragma unroll 8
      for (int j = 0; j < 64; ++j) {
        const float a = A_s[rg * 65 + j];
        const float4 xv = *(const float4*)&x_s[(jc * 64 + j) * FF + fg * 4];
        acc.x += a * xv.x;
        acc.y += a * xv.y;
        acc.z += a * xv.z;
        acc.w += a * xv.w;
      }
    }
    *(float4*)&Ax[((size_t)bt * NN + rt * 64 + rg) * FF + fg * 4] = acc;
  }
}

// ---------------------------------------------------------------------------
// K2: one block per b, 1024 threads (16 waves), all TT steps in-block.
// Register-pressure-aware v2 (round 3 spilled: 64 persistent floats vs 64
// arch VGPRs): persistent state is now only c_r[32] + bias.
//   h-hi plane: LDS, DOUBLE-buffered hFH[2][..] — chunk epilogue writes
//     h(t+1) straight into buffer (t+1)&1; reads come from t&1. No hreg.
//   h-lo plane: global, double-buffered (L2-resident, 128 KB/b); same-CU
//     store->load coherence via block L1 + __syncthreads vmcnt drain.
// Per step, 8 chunks of 32 nodes:
//   phase A: wave w (rt=w>>3, hc=w&7): 16x16 tile of Ah = A@h; A-frags from
//     global (L1-hot), h-hi from LDS, h-lo from global. C-write into region.
//   phase B: gate tiles g*8+hc, row tile rt -> lane holds i,f,g,o of one
//     hidden column -> LSTM pointwise in registers (c in regs).
//   epilogue: h(t+1) -> hi: LDS[nxt], lo: global[nxt]. B2 sync.
// LDS: hFH 2x64K + region 20.5K = 148.5 KB. Grid 32 -> 1 block/CU.
// ---------------------------------------------------------------------------
__global__ __launch_bounds__(1024) void k2_b(
    const _Float16* __restrict__ AfH, const _Float16* __restrict__ AfL,
    const _Float16* __restrict__ WfH, const _Float16* __restrict__ WfL,
    const float* __restrict__ Ax, const float* __restrict__ gcnb,
    _Float16* __restrict__ hGL, float* __restrict__ h32) {
  const int b = blockIdx.x;
  const int tid = threadIdx.x;
  const int w = tid >> 6, l = tid & 63, quad = l >> 4, lo16 = l & 15;
  const int rt = w >> 3;  // row-tile within chunk (0/1)
  const int hc = w & 7;   // hidden-col tile

  __shared__ _Float16 hFH[2][8 * 8 * 512];  // h-hi frags, double-buffered
  __shared__ float region[32 * 164];  // Ah (0..127) | Ax (128..143) | 0 (144..159)

  // ---- init: hFH[0] = 0 (h(-1)=0 hi); zero pad cols 144..159 ----
  {
    const half8 z = {};
    for (int i = tid; i < 4096; i += 1024) *(half8*)&hFH[0][i * 8] = z;
    if (tid < 512) region[(tid >> 4) * 164 + 144 + (tid & 15)] = 0.f;
  }

  // bias registers: this thread's hidden col = hc*16+lo16, gates i,f,g,o
  float bi[4];
#pragma unroll
  for (int g = 0; g < 4; ++g) bi[g] = gcnb[g * HH + hc * 16 + lo16];

  float c_r[32];  // cell state: (chunk rc, r) -> node rc*32 + rt*16 + quad*4 + r
#pragma unroll
  for (int i = 0; i < 32; ++i) c_r[i] = 0.f;

  // epilogue frag coords: node = rc*32 + rt*16 + quad*4 + r
  //   -> kc=rc, lane-pos lp, slot j0
  const int lp = (rt * 2 + (quad >> 1)) * 16 + lo16;
  const int j0 = (quad & 1) * 4;

  __syncthreads();  // hFH[0] init visible

  for (int t = 0; t < TT; ++t) {
    const int pc = t & 1;       // read buffers (LDS hi, global lo)
    const int pn = pc ^ 1;      // write buffers
    // lo-plane read base for this wave's hc (advance by kc*8*512 per kc)
    const size_t loR = (((size_t)pc * BB + b) * 64 + hc) * 512 + l * 8;

#pragma unroll
    for (int rc = 0; rc < 8; ++rc) {
      // ---- phase A: one 16x16 tile per wave ----
      f32x4 accA = (f32x4){0.f, 0.f, 0.f, 0.f};
      const size_t abase = (((size_t)b * 16 + 2 * rc + rt) * 8) * 512 + l * 8;
      for (int kc = 0; kc < 8; ++kc) {
        const half8 aH = *(const half8*)&AfH[abase + (size_t)kc * 512];
        const half8 aL = *(const half8*)&AfL[abase + (size_t)kc * 512];
        const half8 bH = *(const half8*)&hFH[pc][(kc * 8 + hc) * 512 + l * 8];
        const half8 bL = *(const half8*)&hGL[loR + (size_t)kc * 4096];
        accA = __builtin_amdgcn_mfma_f32_16x16x32_f16(aL, bH, accA, 0, 0, 0);
        accA = __builtin_amdgcn_mfma_f32_16x16x32_f16(aH, bL, accA, 0, 0, 0);
        accA = __builtin_amdgcn_mfma_f32_16x16x32_f16(aH, bH, accA, 0, 0, 0);
      }
      // stage Ax[t] chunk -> region cols 128..143
      if (tid < 512) {
        const int r = tid >> 4, f = tid & 15;
        region[r * 164 + 128 + f] =
            Ax[(((size_t)(b * TT + t)) * NN + rc * 32 + r) * FF + f];
      }
      // C-write Ah (col=lane&15, row=quad*4+reg)
#pragma unroll
      for (int r = 0; r < 4; ++r)
        region[(rt * 16 + quad * 4 + r) * 164 + hc * 16 + lo16] = accA[r];
      __syncthreads();  // B1: Ah + Ax staged

      // ---- phase B: 4 gate tiles (i,f,g,o of hidden tile hc), row tile rt ----
      f32x4 acc[4];
#pragma unroll
      for (int g = 0; g < 4; ++g) acc[g] = (f32x4){0.f, 0.f, 0.f, 0.f};

      for (int kc = 0; kc < 5; ++kc) {
        const float* src = &region[(rt * 16 + lo16) * 164 + kc * 32 + quad * 8];
        const float4 v0 = *(const float4*)src;
        const float4 v1 = *(const float4*)(src + 4);
        float av[8] = {v0.x, v0.y, v0.z, v0.w, v1.x, v1.y, v1.z, v1.w};
        half8 pH, pL;
        split8(av, pH, pL);
#pragma unroll
        for (int g = 0; g < 4; ++g) {
          const size_t woff = ((size_t)(kc * 32 + g * 8 + hc)) * 512 + l * 8;
          const half8 wH = *(const half8*)&WfH[woff];
          const half8 wL = *(const half8*)&WfL[woff];
          acc[g] = __builtin_amdgcn_mfma_f32_16x16x32_f16(pL, wH, acc[g], 0, 0, 0);
          acc[g] = __builtin_amdgcn_mfma_f32_16x16x32_f16(pH, wL, acc[g], 0, 0, 0);
          acc[g] = __builtin_amdgcn_mfma_f32_16x16x32_f16(pH, wH, acc[g], 0, 0, 0);
        }
      }

      // ---- LSTM pointwise in registers; h(t+1) straight to frag stores ----
      half4 h4, l4;
#pragma unroll
      for (int r = 0; r < 4; ++r) {
        const float iv = sigf(acc[0][r] + bi[0]);
        const float fv = sigf(acc[1][r] + bi[1]);
        const float gv = tanhfast(acc[2][r] + bi[2]);
        const float ov = sigf(acc[3][r] + bi[3]);
        const float cnew = fv * c_r[rc * 4 + r] + iv * gv;
        c_r[rc * 4 + r] = cnew;
        const float hv = ov * tanhfast(cnew);
        const _Float16 hh = (_Float16)hv;
        h4[r] = hh;
        l4[r] = (_Float16)(hv - (float)hh);
        if (t == TT - 1 && rc == 0) {
          const int node = rt * 16 + quad * 4 + r;
          h32[((size_t)b * 32 + node) * HH + hc * 16 + lo16] = hv;
        }
      }
      if (t != TT - 1) {
        // hi -> LDS next buffer (disjoint from read buffer pc)
        *(half4*)&hFH[pn][(rc * 8 + hc) * 512 + lp * 8 + j0] = h4;
        // lo -> global next buffer
        *(half4*)&hGL[(((size_t)pn * BB + b) * 64 + rc * 8 + hc) * 512 + lp * 8 + j0] = l4;
      }
      __syncthreads();  // B2: region reads done; chunk-7 B2 also fences
                        // hi/lo next-buffer writes for next step (vmcnt drain)
    }
  }
}

// ---------------------------------------------------------------------------
// Tail: GRU over t + fc5/fc2/fc3/fc4. grid = B, 384 threads.
// h32 layout: [b][node 0..31][128] (only node tile 0 is stored; tsi=5 < 32).
// ---------------------------------------------------------------------------
__global__ __launch_bounds__(384) void k_tail(
    const float* __restrict__ x, const float* __restrict__ h32,
    const int* __restrict__ tsi_p, const float* __restrict__ gruWih,
    const float* __restrict__ gruWhh, const float* __restrict__ gru_bih,
    const float* __restrict__ gru_bhh, const float* __restrict__ fc2W,
    const float* __restrict__ fc2b, const float* __restrict__ fc3W,
    const float* __restrict__ fc3b, const float* __restrict__ fc4W,
    const float* __restrict__ fc4b, const float* __restrict__ fc5W,
    const float* __restrict__ fc5b, float* __restrict__ out) {
  const int b = blockIdx.x;
  const int m = threadIdx.x;
  const int tsi = tsi_p[0];

  __shared__ float h_s[HH];
  __shared__ float xts[TT * FF];
  __shared__ float sum_s[384];
  __shared__ float gh_s[384];
  __shared__ float hc_s[2 * HH];
  __shared__ float xr_s[HH];
  __shared__ float f2_s[HH];
  __shared__ float f3_s[64];

  float4 whh[32];
#pragma unroll
  for (int q = 0; q < 32; ++q) whh[q] = *(const float4*)&gruWhh[(size_t)m * HH + q * 4];
  float4 wih[4];
#pragma unroll
  for (int q = 0; q < 4; ++q) wih[q] = *(const float4*)&gruWih[(size_t)m * FF + q * 4];
  const float bih_r = gru_bih[m];
  const float bhh_r = gru_bhh[m];

  {
    const int t = m >> 4, f = m & 15;
    xts[m] = x[(((size_t)b * TT + t) * NN + tsi) * FF + f];
  }
  if (m < HH) h_s[m] = 0.f;
  __syncthreads();

  for (int t = 0; t < TT; ++t) {
    float gi = bih_r;
#pragma unroll
    for (int q = 0; q < 4; ++q) {
      const float4 xv = *(const float4*)&xts[t * FF + q * 4];
      gi += wih[q].x * xv.x + wih[q].y * xv.y + wih[q].z * xv.z + wih[q].w * xv.w;
    }
    float gh = bhh_r;
#pragma unroll
    for (int q = 0; q < 32; ++q) {
      const float4 hv = *(const float4*)&h_s[q * 4];
      gh += whh[q].x * hv.x + whh[q].y * hv.y + whh[q].z * hv.z + whh[q].w * hv.w;
    }
    sum_s[m] = gi + gh;
    gh_s[m] = gh;
    __syncthreads();
    float hnew = 0.f;
    if (m < HH) {
      const float r = sigf(sum_s[m]);
      const float z = sigf(sum_s[HH + m]);
      const float ghn = gh_s[2 * HH + m];
      const float nn = tanhfast(sum_s[2 * HH + m] - ghn + r * ghn);
      hnew = (1.f - z) * nn + z * h_s[m];
    }
    __syncthreads();
    if (m < HH) h_s[m] = hnew;
    __syncthreads();
  }

  if (m < HH) {
    hc_s[m] = h_s[m];
    xr_s[m] = fmaxf(h32[((size_t)b * 32 + tsi) * HH + m], 0.f);
  }
  __syncthreads();
  if (m < HH) {
    float v = fc5b[m];
    const float* wr = fc5W + (size_t)m * HH;
#pragma unroll 8
    for (int k = 0; k < HH; k += 4) {
      const float4 wv = *(const float4*)(wr + k);
      v += xr_s[k] * wv.x + xr_s[k + 1] * wv.y + xr_s[k + 2] * wv.z + xr_s[k + 3] * wv.w;
    }
    hc_s[HH + m] = v;
  }
  __syncthreads();
  if (m < HH) {
    float v = fc2b[m];
    const float* wr = fc2W + (size_t)m * 2 * HH;
#pragma unroll 8
    for (int k = 0; k < 2 * HH; k += 4) {
      const float4 wv = *(const float4*)(wr + k);
      v += hc_s[k] * wv.x + hc_s[k + 1] * wv.y + hc_s[k + 2] * wv.z + hc_s[k + 3] * wv.w;
    }
    f2_s[m] = fmaxf(v, 0.f);
  }
  __syncthreads();
  if (m < 64) {
    float v = fc3b[m];
    const float* wr = fc3W + (size_t)m * HH;
#pragma unroll 8
    for (int k = 0; k < HH; k += 4) {
      const float4 wv = *(const float4*)(wr + k);
      v += f2_s[k] * wv.x + f2_s[k + 1] * wv.y + f2_s[k + 2] * wv.z + f2_s[k + 3] * wv.w;
    }
    f3_s[m] = fmaxf(v, 0.f);
  }
  __syncthreads();
  if (m < 24) {
    float v = fc4b[m];
    const float* wr = fc4W + (size_t)m * 64;
#pragma unroll
    for (int k = 0; k < 64; k += 4) {
      const float4 wv = *(const float4*)(wr + k);
      v += f3_s[k] * wv.x + f3_s[k + 1] * wv.y + f3_s[k + 2] * wv.z + f3_s[k + 3] * wv.w;
    }
    out[b * 24 + m] = v;
  }
}

// ---------------------------------------------------------------------------
extern "C" void kernel_launch(void* const* d_in, const int* in_sizes, int n_in,
                              void* d_out, int out_size, void* d_ws, size_t ws_size,
                              hipStream_t stream) {
  const float* x = (const float*)d_in[0];
  const float* adj = (const float*)d_in[1];
  const int* tsi = (const int*)d_in[2];
  const float* gcnW = (const float*)d_in[3];
  const float* gcnb = (const float*)d_in[4];
  const float* gruWih = (const float*)d_in[5];
  const float* gruWhh = (const float*)d_in[6];
  const float* gru_bih = (const float*)d_in[7];
  const float* gru_bhh = (const float*)d_in[8];
  const float* fc2W = (const float*)d_in[9];
  const float* fc2b = (const float*)d_in[10];
  const float* fc3W = (const float*)d_in[11];
  const float* fc3b = (const float*)d_in[12];
  const float* fc4W = (const float*)d_in[13];
  const float* fc4b = (const float*)d_in[14];
  const float* fc5W = (const float*)d_in[15];
  const float* fc5b = (const float*)d_in[16];
  float* out = (float*)d_out;

  // ws layout (elements)
  float* Ax = (float*)d_ws;                           // 32*24*256*16 = 3,145,728 f
  float* h32 = Ax + 3145728;                          // 32*32*128   =   131,072 f
  _Float16* AfH = (_Float16*)(h32 + 131072);          // 32*16*8*512 = 2,097,152 h
  _Float16* AfL = AfH + 2097152;                      // 2,097,152 h
  _Float16* WfH = AfL + 2097152;                      // 5*32*512    =    81,920 h
  _Float16* WfL = WfH + 81920;                        // 81,920 h
  _Float16* hGL = WfL + 81920;                        // 2*32*64*512 = 2,097,152 h (lo dbuf)

  // zero hGL parity-0 half (t=0 reads it as h(-1)-lo = 0): 32*64*512 halfs = 2MB
  hipMemsetAsync(hGL, 0, (size_t)BB * 64 * 512 * 2, stream);

  k0_wswz<<<dim3(160), 64, 0, stream>>>(gcnW, WfH, WfL);
  k0_aswz<<<dim3(128, BB), 64, 0, stream>>>(adj, AfH, AfL);
  k1_ax<<<dim3(BB * TT), 256, 0, stream>>>(adj, x, Ax);

  // one block per b; entire 24-step scan runs in-block (no cross-block sync)
  k2_b<<<dim3(BB), 1024, 0, stream>>>(AfH, AfL, WfH, WfL, Ax, gcnb, hGL, h32);

  k_tail<<<dim3(BB), 384, 0, stream>>>(x, h32, tsi, gruWih, gruWhh, gru_bih, gru_bhh, fc2W,
                                       fc2b, fc3W, fc3b, fc4W, fc4b, fc5W, fc5b, out);
}

// Round 5
// 4592.170 us; speedup vs baseline: 1.1998x; 1.1315x over previous
//
#include <hip/hip_runtime.h>
#include <math.h>

#define BB 32
#define TT 24
#define NN 256
#define FF 16
#define HH 128
#define G4 512  // 4*H

typedef _Float16 half8 __attribute__((ext_vector_type(8)));
typedef _Float16 half4 __attribute__((ext_vector_type(4)));
typedef float f32x4 __attribute__((ext_vector_type(4)));

__device__ __forceinline__ float sigf(float x) { return 1.f / (1.f + __expf(-x)); }
__device__ __forceinline__ float tanhfast(float x) { return 1.f - 2.f / (__expf(2.f * x) + 1.f); }

// fp32 -> (hi, lo) fp16 split: v ~= hi + lo, residual ~2^-22 relative.
__device__ __forceinline__ void split8(const float* v, half8& hi, half8& lo) {
#pragma unroll
  for (int i = 0; i < 8; ++i) {
    const _Float16 h = (_Float16)v[i];
    hi[i] = h;
    lo[i] = (_Float16)(v[i] - (float)h);
  }
}

// ---------------------------------------------------------------------------
// K0a: pre-split+swizzle gcn_W into B-frag tiles.
// Wfrag[kc(5)][ct(32)][lane][8]: element W_op[k][n]:
//   kc<4 : gcnW[16 + kc*32 + k][ct*16 + n]   (h part, rows 16..143)
//   kc==4: k<16 ? gcnW[k][ct*16+n] : 0       (x part zero-padded to K=32)
// with k = (lane>>4)*8 + j, n = lane&15.
// ---------------------------------------------------------------------------
__global__ __launch_bounds__(64) void k0_wswz(const float* __restrict__ gcnW,
                                              _Float16* __restrict__ WfH,
                                              _Float16* __restrict__ WfL) {
  const int bid = blockIdx.x;  // kc*32 + ct, 0..159
  const int kc = bid >> 5, ct = bid & 31;
  const int l = threadIdx.x, quad = l >> 4, lo16 = l & 15;
  float v[8];
#pragma unroll
  for (int j = 0; j < 8; ++j) {
    const int k = quad * 8 + j;
    float val = 0.f;
    if (kc < 4) val = gcnW[(size_t)(16 + kc * 32 + k) * G4 + ct * 16 + lo16];
    else if (k < 16) val = gcnW[(size_t)k * G4 + ct * 16 + lo16];
    v[j] = val;
  }
  half8 hi, lo;
  split8(v, hi, lo);
  const size_t off = (size_t)bid * 512 + l * 8;
  *(half8*)&WfH[off] = hi;
  *(half8*)&WfL[off] = lo;
}

// ---------------------------------------------------------------------------
// K0b: pre-split+swizzle adjacency (adj[:, T-1]) into A-frag tiles.
// Afrag[b][nt16(16)][kc(8)][lane][8]: element adj[b][T-1][m][k],
//   m = nt16*16 + (lane&15), k = kc*32 + (lane>>4)*8 + j.
// ---------------------------------------------------------------------------
__global__ __launch_bounds__(64) void k0_aswz(const float* __restrict__ adj,
                                              _Float16* __restrict__ AfH,
                                              _Float16* __restrict__ AfL) {
  const int nt16 = blockIdx.x >> 3, kc = blockIdx.x & 7;
  const int b = blockIdx.y;
  const int l = threadIdx.x, quad = l >> 4, lo16 = l & 15;
  const float* src =
      adj + (((size_t)(b * TT + TT - 1)) * NN + nt16 * 16 + lo16) * NN + kc * 32 + quad * 8;
  const float4 v0 = *(const float4*)src;
  const float4 v1 = *(const float4*)(src + 4);
  float v[8] = {v0.x, v0.y, v0.z, v0.w, v1.x, v1.y, v1.z, v1.w};
  half8 hi, lo;
  split8(v, hi, lo);
  const size_t off = (((size_t)b * 16 + nt16) * 8 + kc) * 512 + l * 8;
  *(half8*)&AfH[off] = hi;
  *(half8*)&AfL[off] = lo;
}

// ---------------------------------------------------------------------------
// K1: Ax[b,t,n,f] = sum_j A[b,n,j] * x[b,t,j,f]   (fp32, parallel over b,t)
// ---------------------------------------------------------------------------
__global__ __launch_bounds__(256) void k1_ax(const float* __restrict__ adj,
                                             const float* __restrict__ x,
                                             float* __restrict__ Ax) {
  const int bt = blockIdx.x;
  const int b = bt / TT;
  const float* Abase = adj + ((size_t)(b * TT + (TT - 1)) * NN) * NN;
  const float* xbase = x + (size_t)bt * NN * FF;

  __shared__ float x_s[NN * FF];
  __shared__ float A_s[64 * 65];

  for (int i4 = threadIdx.x; i4 < (NN * FF) / 4; i4 += 256) {
    ((float4*)x_s)[i4] = ((const float4*)xbase)[i4];
  }
  const int rg = threadIdx.x >> 2;
  const int fg = threadIdx.x & 3;

  for (int rt = 0; rt < 4; ++rt) {
    float4 acc = make_float4(0.f, 0.f, 0.f, 0.f);
    for (int jc = 0; jc < 4; ++jc) {
      __syncthreads();
      for (int i = threadIdx.x; i < 64 * 64; i += 256) {
        const int r = i >> 6, j = i & 63;
        A_s[r * 65 + j] = Abase[(size_t)(rt * 64 + r) * NN + jc * 64 + j];
      }
      __syncthreads();
#pragma unroll 8
      for (int j = 0; j < 64; ++j) {
        const float a = A_s[rg * 65 + j];
        const float4 xv = *(const float4*)&x_s[(jc * 64 + j) * FF + fg * 4];
        acc.x += a * xv.x;
        acc.y += a * xv.y;
        acc.z += a * xv.z;
        acc.w += a * xv.w;
      }
    }
    *(float4*)&Ax[((size_t)bt * NN + rt * 64 + rg) * FF + fg * 4] = acc;
  }
}

// ---------------------------------------------------------------------------
// K2 v3: one block per b, 1024 threads (16 waves), all TT steps in-block.
// Register budget: 1024-thr workgroup => 128 regs/thread total, compiler
// splits 64 arch + 64 accum. v2 spilled c_r[32] (FETCH 1.07 GB scratch).
// v3: ZERO persistent arrays —
//   c: global, [b][rc][tid] float4 — coalesced, 1 load + 1 store per chunk,
//      512 KB/XCD => L2-resident. Loaded at chunk start (hidden under MFMA).
//   h-hi: LDS double-buffer (as v2).  h-lo: global double-buffer (as v2).
// Per step, 8 chunks of 32 nodes:
//   phase A: wave w (rt=w>>3, hc=w&7): 16x16 tile of Ah = A@h.
//   phase B: gate tiles g*8+hc, row tile rt -> lane holds i,f,g,o of one
//     hidden column -> LSTM pointwise in registers.
//   epilogue: h(t+1) hi->LDS[nxt], lo->global[nxt]; c->global. B2 sync.
// LDS: hFH 2x64K + region 20.5K = 148.5 KB. Grid 32 -> 1 block/CU.
// ---------------------------------------------------------------------------
__global__ __launch_bounds__(1024) void k2_b(
    const _Float16* __restrict__ AfH, const _Float16* __restrict__ AfL,
    const _Float16* __restrict__ WfH, const _Float16* __restrict__ WfL,
    const float* __restrict__ Ax, const float* __restrict__ gcnb,
    _Float16* __restrict__ hGL, float* __restrict__ cG,
    float* __restrict__ h32) {
  const int b = blockIdx.x;
  const int tid = threadIdx.x;
  const int w = tid >> 6, l = tid & 63, quad = l >> 4, lo16 = l & 15;
  const int rt = w >> 3;  // row-tile within chunk (0/1)
  const int hc = w & 7;   // hidden-col tile

  __shared__ _Float16 hFH[2][8 * 8 * 512];  // h-hi frags, double-buffered
  __shared__ float region[32 * 164];  // Ah (0..127) | Ax (128..143) | 0 (144..159)

  // ---- init: hFH[0] = 0 (h(-1)=0 hi); zero pad cols 144..159 ----
  {
    const half8 z = {};
    for (int i = tid; i < 4096; i += 1024) *(half8*)&hFH[0][i * 8] = z;
    if (tid < 512) region[(tid >> 4) * 164 + 144 + (tid & 15)] = 0.f;
  }

  // bias registers: this thread's hidden col = hc*16+lo16, gates i,f,g,o
  float bi[4];
#pragma unroll
  for (int g = 0; g < 4; ++g) bi[g] = gcnb[g * HH + hc * 16 + lo16];

  // epilogue frag coords: node = rc*32 + rt*16 + quad*4 + r
  //   -> kc=rc, lane-pos lp, slot j0
  const int lp = (rt * 2 + (quad >> 1)) * 16 + lo16;
  const int j0 = (quad & 1) * 4;

  union F4 { float4 v; float a[4]; };

  __syncthreads();  // hFH[0] init visible

  for (int t = 0; t < TT; ++t) {
    const int pc = t & 1;       // read buffers (LDS hi, global lo)
    const int pn = pc ^ 1;      // write buffers
    // lo-plane read base for this wave's hc (advance by kc*8*512 per kc)
    const size_t loR = (((size_t)pc * BB + b) * 64 + hc) * 512 + l * 8;

#pragma unroll
    for (int rc = 0; rc < 8; ++rc) {
      // c load for this chunk (latency hidden under phase A MFMAs)
      F4 c4;
      c4.v = *(const float4*)&cG[(((size_t)b * 8 + rc) * 1024 + tid) * 4];

      // ---- phase A: one 16x16 tile per wave ----
      f32x4 accA = (f32x4){0.f, 0.f, 0.f, 0.f};
      const size_t abase = (((size_t)b * 16 + 2 * rc + rt) * 8) * 512 + l * 8;
      for (int kc = 0; kc < 8; ++kc) {
        const half8 aH = *(const half8*)&AfH[abase + (size_t)kc * 512];
        const half8 aL = *(const half8*)&AfL[abase + (size_t)kc * 512];
        const half8 bH = *(const half8*)&hFH[pc][(kc * 8 + hc) * 512 + l * 8];
        const half8 bL = *(const half8*)&hGL[loR + (size_t)kc * 4096];
        accA = __builtin_amdgcn_mfma_f32_16x16x32_f16(aL, bH, accA, 0, 0, 0);
        accA = __builtin_amdgcn_mfma_f32_16x16x32_f16(aH, bL, accA, 0, 0, 0);
        accA = __builtin_amdgcn_mfma_f32_16x16x32_f16(aH, bH, accA, 0, 0, 0);
      }
      // stage Ax[t] chunk -> region cols 128..143
      if (tid < 512) {
        const int r = tid >> 4, f = tid & 15;
        region[r * 164 + 128 + f] =
            Ax[(((size_t)(b * TT + t)) * NN + rc * 32 + r) * FF + f];
      }
      // C-write Ah (col=lane&15, row=quad*4+reg)
#pragma unroll
      for (int r = 0; r < 4; ++r)
        region[(rt * 16 + quad * 4 + r) * 164 + hc * 16 + lo16] = accA[r];
      __syncthreads();  // B1: Ah + Ax staged

      // ---- phase B: 4 gate tiles (i,f,g,o of hidden tile hc), row tile rt ----
      f32x4 acc[4];
#pragma unroll
      for (int g = 0; g < 4; ++g) acc[g] = (f32x4){0.f, 0.f, 0.f, 0.f};

      for (int kc = 0; kc < 5; ++kc) {
        const float* src = &region[(rt * 16 + lo16) * 164 + kc * 32 + quad * 8];
        const float4 v0 = *(const float4*)src;
        const float4 v1 = *(const float4*)(src + 4);
        float av[8] = {v0.x, v0.y, v0.z, v0.w, v1.x, v1.y, v1.z, v1.w};
        half8 pH, pL;
        split8(av, pH, pL);
#pragma unroll
        for (int g = 0; g < 4; ++g) {
          const size_t woff = ((size_t)(kc * 32 + g * 8 + hc)) * 512 + l * 8;
          const half8 wH = *(const half8*)&WfH[woff];
          const half8 wL = *(const half8*)&WfL[woff];
          acc[g] = __builtin_amdgcn_mfma_f32_16x16x32_f16(pL, wH, acc[g], 0, 0, 0);
          acc[g] = __builtin_amdgcn_mfma_f32_16x16x32_f16(pH, wL, acc[g], 0, 0, 0);
          acc[g] = __builtin_amdgcn_mfma_f32_16x16x32_f16(pH, wH, acc[g], 0, 0, 0);
        }
      }

      // ---- LSTM pointwise in registers; h(t+1) straight to frag stores ----
      half4 h4, l4;
      F4 cn;
#pragma unroll
      for (int r = 0; r < 4; ++r) {
        const float iv = sigf(acc[0][r] + bi[0]);
        const float fv = sigf(acc[1][r] + bi[1]);
        const float gv = tanhfast(acc[2][r] + bi[2]);
        const float ov = sigf(acc[3][r] + bi[3]);
        const float cnew = fv * c4.a[r] + iv * gv;
        cn.a[r] = cnew;
        const float hv = ov * tanhfast(cnew);
        const _Float16 hh = (_Float16)hv;
        h4[r] = hh;
        l4[r] = (_Float16)(hv - (float)hh);
        if (t == TT - 1 && rc == 0) {
          const int node = rt * 16 + quad * 4 + r;
          h32[((size_t)b * 32 + node) * HH + hc * 16 + lo16] = hv;
        }
      }
      *(float4*)&cG[(((size_t)b * 8 + rc) * 1024 + tid) * 4] = cn.v;
      if (t != TT - 1) {
        // hi -> LDS next buffer (disjoint from read buffer pc)
        *(half4*)&hFH[pn][(rc * 8 + hc) * 512 + lp * 8 + j0] = h4;
        // lo -> global next buffer
        *(half4*)&hGL[(((size_t)pn * BB + b) * 64 + rc * 8 + hc) * 512 + lp * 8 + j0] = l4;
      }
      __syncthreads();  // B2: region reads done; chunk-7 B2 also fences
                        // hi/lo next-buffer writes for next step (vmcnt drain)
    }
  }
}

// ---------------------------------------------------------------------------
// Tail: GRU over t + fc5/fc2/fc3/fc4. grid = B, 384 threads.
// h32 layout: [b][node 0..31][128] (only node tile 0 is stored; tsi=5 < 32).
// ---------------------------------------------------------------------------
__global__ __launch_bounds__(384) void k_tail(
    const float* __restrict__ x, const float* __restrict__ h32,
    const int* __restrict__ tsi_p, const float* __restrict__ gruWih,
    const float* __restrict__ gruWhh, const float* __restrict__ gru_bih,
    const float* __restrict__ gru_bhh, const float* __restrict__ fc2W,
    const float* __restrict__ fc2b, const float* __restrict__ fc3W,
    const float* __restrict__ fc3b, const float* __restrict__ fc4W,
    const float* __restrict__ fc4b, const float* __restrict__ fc5W,
    const float* __restrict__ fc5b, float* __restrict__ out) {
  const int b = blockIdx.x;
  const int m = threadIdx.x;
  const int tsi = tsi_p[0];

  __shared__ float h_s[HH];
  __shared__ float xts[TT * FF];
  __shared__ float sum_s[384];
  __shared__ float gh_s[384];
  __shared__ float hc_s[2 * HH];
  __shared__ float xr_s[HH];
  __shared__ float f2_s[HH];
  __shared__ float f3_s[64];

  float4 whh[32];
#pragma unroll
  for (int q = 0; q < 32; ++q) whh[q] = *(const float4*)&gruWhh[(size_t)m * HH + q * 4];
  float4 wih[4];
#pragma unroll
  for (int q = 0; q < 4; ++q) wih[q] = *(const float4*)&gruWih[(size_t)m * FF + q * 4];
  const float bih_r = gru_bih[m];
  const float bhh_r = gru_bhh[m];

  {
    const int t = m >> 4, f = m & 15;
    xts[m] = x[(((size_t)b * TT + t) * NN + tsi) * FF + f];
  }
  if (m < HH) h_s[m] = 0.f;
  __syncthreads();

  for (int t = 0; t < TT; ++t) {
    float gi = bih_r;
#pragma unroll
    for (int q = 0; q < 4; ++q) {
      const float4 xv = *(const float4*)&xts[t * FF + q * 4];
      gi += wih[q].x * xv.x + wih[q].y * xv.y + wih[q].z * xv.z + wih[q].w * xv.w;
    }
    float gh = bhh_r;
#pragma unroll
    for (int q = 0; q < 32; ++q) {
      const float4 hv = *(const float4*)&h_s[q * 4];
      gh += whh[q].x * hv.x + whh[q].y * hv.y + whh[q].z * hv.z + whh[q].w * hv.w;
    }
    sum_s[m] = gi + gh;
    gh_s[m] = gh;
    __syncthreads();
    float hnew = 0.f;
    if (m < HH) {
      const float r = sigf(sum_s[m]);
      const float z = sigf(sum_s[HH + m]);
      const float ghn = gh_s[2 * HH + m];
      const float nn = tanhfast(sum_s[2 * HH + m] - ghn + r * ghn);
      hnew = (1.f - z) * nn + z * h_s[m];
    }
    __syncthreads();
    if (m < HH) h_s[m] = hnew;
    __syncthreads();
  }

  if (m < HH) {
    hc_s[m] = h_s[m];
    xr_s[m] = fmaxf(h32[((size_t)b * 32 + tsi) * HH + m], 0.f);
  }
  __syncthreads();
  if (m < HH) {
    float v = fc5b[m];
    const float* wr = fc5W + (size_t)m * HH;
#pragma unroll 8
    for (int k = 0; k < HH; k += 4) {
      const float4 wv = *(const float4*)(wr + k);
      v += xr_s[k] * wv.x + xr_s[k + 1] * wv.y + xr_s[k + 2] * wv.z + xr_s[k + 3] * wv.w;
    }
    hc_s[HH + m] = v;
  }
  __syncthreads();
  if (m < HH) {
    float v = fc2b[m];
    const float* wr = fc2W + (size_t)m * 2 * HH;
#pragma unroll 8
    for (int k = 0; k < 2 * HH; k += 4) {
      const float4 wv = *(const float4*)(wr + k);
      v += hc_s[k] * wv.x + hc_s[k + 1] * wv.y + hc_s[k + 2] * wv.z + hc_s[k + 3] * wv.w;
    }
    f2_s[m] = fmaxf(v, 0.f);
  }
  __syncthreads();
  if (m < 64) {
    float v = fc3b[m];
    const float* wr = fc3W + (size_t)m * HH;
#pragma unroll 8
    for (int k = 0; k < HH; k += 4) {
      const float4 wv = *(const float4*)(wr + k);
      v += f2_s[k] * wv.x + f2_s[k + 1] * wv.y + f2_s[k + 2] * wv.z + f2_s[k + 3] * wv.w;
    }
    f3_s[m] = fmaxf(v, 0.f);
  }
  __syncthreads();
  if (m < 24) {
    float v = fc4b[m];
    const float* wr = fc4W + (size_t)m * 64;
#pragma unroll
    for (int k = 0; k < 64; k += 4) {
      const float4 wv = *(const float4*)(wr + k);
      v += f3_s[k] * wv.x + f3_s[k + 1] * wv.y + f3_s[k + 2] * wv.z + f3_s[k + 3] * wv.w;
    }
    out[b * 24 + m] = v;
  }
}

// ---------------------------------------------------------------------------
extern "C" void kernel_launch(void* const* d_in, const int* in_sizes, int n_in,
                              void* d_out, int out_size, void* d_ws, size_t ws_size,
                              hipStream_t stream) {
  const float* x = (const float*)d_in[0];
  const float* adj = (const float*)d_in[1];
  const int* tsi = (const int*)d_in[2];
  const float* gcnW = (const float*)d_in[3];
  const float* gcnb = (const float*)d_in[4];
  const float* gruWih = (const float*)d_in[5];
  const float* gruWhh = (const float*)d_in[6];
  const float* gru_bih = (const float*)d_in[7];
  const float* gru_bhh = (const float*)d_in[8];
  const float* fc2W = (const float*)d_in[9];
  const float* fc2b = (const float*)d_in[10];
  const float* fc3W = (const float*)d_in[11];
  const float* fc3b = (const float*)d_in[12];
  const float* fc4W = (const float*)d_in[13];
  const float* fc4b = (const float*)d_in[14];
  const float* fc5W = (const float*)d_in[15];
  const float* fc5b = (const float*)d_in[16];
  float* out = (float*)d_out;

  // ws layout (elements)
  float* Ax = (float*)d_ws;                           // 32*24*256*16 = 3,145,728 f
  float* h32 = Ax + 3145728;                          // 32*32*128   =   131,072 f
  _Float16* AfH = (_Float16*)(h32 + 131072);          // 32*16*8*512 = 2,097,152 h
  _Float16* AfL = AfH + 2097152;                      // 2,097,152 h
  _Float16* WfH = AfL + 2097152;                      // 5*32*512    =    81,920 h
  _Float16* WfL = WfH + 81920;                        // 81,920 h
  _Float16* hGL = WfL + 81920;                        // 2*32*64*512 = 2,097,152 h (lo dbuf)
  float* cG = (float*)(hGL + 2097152);                // 32*8*1024*4 = 1,048,576 f (cell)

  // zero hGL (h(-1)-lo = 0; parity-1 harmless) + cG (c(-1)=0): contiguous 8 MB
  hipMemsetAsync(hGL, 0, 2097152 * 2 + 1048576 * 4, stream);

  k0_wswz<<<dim3(160), 64, 0, stream>>>(gcnW, WfH, WfL);
  k0_aswz<<<dim3(128, BB), 64, 0, stream>>>(adj, AfH, AfL);
  k1_ax<<<dim3(BB * TT), 256, 0, stream>>>(adj, x, Ax);

  // one block per b; entire 24-step scan runs in-block (no cross-block sync)
  k2_b<<<dim3(BB), 1024, 0, stream>>>(AfH, AfL, WfH, WfL, Ax, gcnb, hGL, cG, h32);

  k_tail<<<dim3(BB), 384, 0, stream>>>(x, h32, tsi, gruWih, gruWhh, gru_bih, gru_bhh, fc2W,
                                       fc2b, fc3W, fc3b, fc4W, fc4b, fc5W, fc5b, out);
}

// Round 6
// 1967.426 us; speedup vs baseline: 2.8004x; 2.3341x over previous
//
#include <hip/hip_runtime.h>
#include <math.h>

#define BB 32
#define TT 24
#define NN 256
#define FF 16
#define HH 128
#define G4 512  // 4*H

typedef _Float16 half8 __attribute__((ext_vector_type(8)));
typedef _Float16 half4 __attribute__((ext_vector_type(4)));
typedef float f32x4 __attribute__((ext_vector_type(4)));

__device__ __forceinline__ float sigf(float x) { return 1.f / (1.f + __expf(-x)); }
__device__ __forceinline__ float tanhfast(float x) { return 1.f - 2.f / (__expf(2.f * x) + 1.f); }

// fp32 -> (hi, lo) fp16 split: v ~= hi + lo, residual ~2^-22 relative.
__device__ __forceinline__ void split8(const float* v, half8& hi, half8& lo) {
#pragma unroll
  for (int i = 0; i < 8; ++i) {
    const _Float16 h = (_Float16)v[i];
    hi[i] = h;
    lo[i] = (_Float16)(v[i] - (float)h);
  }
}

// ---------------------------------------------------------------------------
// K0a: pre-split+swizzle gcn_W into B-frag tiles.
// Wfrag[kc(5)][ct(32)][lane][8]: element W_op[k][n]:
//   kc<4 : gcnW[16 + kc*32 + k][ct*16 + n]   (h part, rows 16..143)
//   kc==4: k<16 ? gcnW[k][ct*16+n] : 0       (x part zero-padded to K=32)
// with k = (lane>>4)*8 + j, n = lane&15.
// ---------------------------------------------------------------------------
__global__ __launch_bounds__(64) void k0_wswz(const float* __restrict__ gcnW,
                                              _Float16* __restrict__ WfH,
                                              _Float16* __restrict__ WfL) {
  const int bid = blockIdx.x;  // kc*32 + ct, 0..159
  const int kc = bid >> 5, ct = bid & 31;
  const int l = threadIdx.x, quad = l >> 4, lo16 = l & 15;
  float v[8];
#pragma unroll
  for (int j = 0; j < 8; ++j) {
    const int k = quad * 8 + j;
    float val = 0.f;
    if (kc < 4) val = gcnW[(size_t)(16 + kc * 32 + k) * G4 + ct * 16 + lo16];
    else if (k < 16) val = gcnW[(size_t)k * G4 + ct * 16 + lo16];
    v[j] = val;
  }
  half8 hi, lo;
  split8(v, hi, lo);
  const size_t off = (size_t)bid * 512 + l * 8;
  *(half8*)&WfH[off] = hi;
  *(half8*)&WfL[off] = lo;
}

// ---------------------------------------------------------------------------
// K0b: pre-split+swizzle adjacency (adj[:, T-1]) into A-frag tiles.
// Afrag[b][nt16(16)][kc(8)][lane][8]: element adj[b][T-1][m][k],
//   m = nt16*16 + (lane&15), k = kc*32 + (lane>>4)*8 + j.
// ---------------------------------------------------------------------------
__global__ __launch_bounds__(64) void k0_aswz(const float* __restrict__ adj,
                                              _Float16* __restrict__ AfH,
                                              _Float16* __restrict__ AfL) {
  const int nt16 = blockIdx.x >> 3, kc = blockIdx.x & 7;
  const int b = blockIdx.y;
  const int l = threadIdx.x, quad = l >> 4, lo16 = l & 15;
  const float* src =
      adj + (((size_t)(b * TT + TT - 1)) * NN + nt16 * 16 + lo16) * NN + kc * 32 + quad * 8;
  const float4 v0 = *(const float4*)src;
  const float4 v1 = *(const float4*)(src + 4);
  float v[8] = {v0.x, v0.y, v0.z, v0.w, v1.x, v1.y, v1.z, v1.w};
  half8 hi, lo;
  split8(v, hi, lo);
  const size_t off = (((size_t)b * 16 + nt16) * 8 + kc) * 512 + l * 8;
  *(half8*)&AfH[off] = hi;
  *(half8*)&AfL[off] = lo;
}

// ---------------------------------------------------------------------------
// K1: Ax[b,t,n,f] = sum_j A[b,n,j] * x[b,t,j,f]   (fp32, parallel over b,t)
// ---------------------------------------------------------------------------
__global__ __launch_bounds__(256) void k1_ax(const float* __restrict__ adj,
                                             const float* __restrict__ x,
                                             float* __restrict__ Ax) {
  const int bt = blockIdx.x;
  const int b = bt / TT;
  const float* Abase = adj + ((size_t)(b * TT + (TT - 1)) * NN) * NN;
  const float* xbase = x + (size_t)bt * NN * FF;

  __shared__ float x_s[NN * FF];
  __shared__ float A_s[64 * 65];

  for (int i4 = threadIdx.x; i4 < (NN * FF) / 4; i4 += 256) {
    ((float4*)x_s)[i4] = ((const float4*)xbase)[i4];
  }
  const int rg = threadIdx.x >> 2;
  const int fg = threadIdx.x & 3;

  for (int rt = 0; rt < 4; ++rt) {
    float4 acc = make_float4(0.f, 0.f, 0.f, 0.f);
    for (int jc = 0; jc < 4; ++jc) {
      __syncthreads();
      for (int i = threadIdx.x; i < 64 * 64; i += 256) {
        const int r = i >> 6, j = i & 63;
        A_s[r * 65 + j] = Abase[(size_t)(rt * 64 + r) * NN + jc * 64 + j];
      }
      __syncthreads();
#pragma unroll 8
      for (int j = 0; j < 64; ++j) {
        const float a = A_s[rg * 65 + j];
        const float4 xv = *(const float4*)&x_s[(jc * 64 + j) * FF + fg * 4];
        acc.x += a * xv.x;
        acc.y += a * xv.y;
        acc.z += a * xv.z;
        acc.w += a * xv.w;
      }
    }
    *(float4*)&Ax[((size_t)bt * NN + rt * 64 + rg) * FF + fg * 4] = acc;
  }
}

// ---------------------------------------------------------------------------
// K2 v4: one block per b, 512 threads (8 waves), all TT steps in-block.
// v3 POST-MORTEM: 1024-thr workgroup caps regs at 128/thread (64 arch + 64
// accum); working set needs ~90 arch -> permanent spill -> 1.07 GB scratch
// FETCH. v4: 512 threads => 2 waves/SIMD => 256-reg budget, zero spill.
// Wave w = hidden-col tile hc (0..7); each wave owns BOTH row tiles rt=0,1:
//   phase A: accA[2], shared bH/bL per kc (one h-frag load feeds 2 MFMAs).
//   phase B: acc[2][4]; one wH/wL load feeds 2 MFMAs (W is rt-independent).
//   pointwise: thread holds i,f,g,o for 8 (rt,r) outputs; c from global
//     [b][rc][tid]x8 (coalesced, L2-resident); h(t+1) hi->LDS dbuf,
//     lo->global dbuf (structure proven in v2/v3).
// LDS: hFH 2x64K + region 20.5K = 148.5 KB. Grid 32 -> 1 block/CU.
// ---------------------------------------------------------------------------
__global__ __launch_bounds__(512) void k2_b(
    const _Float16* __restrict__ AfH, const _Float16* __restrict__ AfL,
    const _Float16* __restrict__ WfH, const _Float16* __restrict__ WfL,
    const float* __restrict__ Ax, const float* __restrict__ gcnb,
    _Float16* __restrict__ hGL, float* __restrict__ cG,
    float* __restrict__ h32) {
  const int b = blockIdx.x;
  const int tid = threadIdx.x;
  const int w = tid >> 6, l = tid & 63, quad = l >> 4, lo16 = l & 15;
  const int hc = w;  // hidden-col tile (0..7)

  __shared__ _Float16 hFH[2][8 * 8 * 512];  // h-hi frags, double-buffered
  __shared__ float region[32 * 164];  // Ah (0..127) | Ax (128..143) | 0 (144..159)

  // ---- init: hFH[0] = 0 (h(-1)=0 hi); zero pad cols 144..159 ----
  {
    const half8 z = {};
    for (int i = tid; i < 4096; i += 512) *(half8*)&hFH[0][i * 8] = z;
    region[(tid >> 4) * 164 + 144 + (tid & 15)] = 0.f;
  }

  // bias registers: this thread's hidden col = hc*16+lo16, gates i,f,g,o
  float bi[4];
#pragma unroll
  for (int g = 0; g < 4; ++g) bi[g] = gcnb[g * HH + hc * 16 + lo16];

  // epilogue frag coords: node = rc*32 + rt*16 + quad*4 + r
  //   -> kc=rc, lane-pos lp(rt) = (rt*2+(quad>>1))*16+lo16, slot j0
  const int lp0 = ((quad >> 1)) * 16 + lo16;
  const int lp1 = (2 + (quad >> 1)) * 16 + lo16;
  const int j0 = (quad & 1) * 4;

  union F4 { float4 v; float a[4]; };

  __syncthreads();  // hFH[0] init visible

  for (int t = 0; t < TT; ++t) {
    const int pc = t & 1;       // read buffers (LDS hi, global lo)
    const int pn = pc ^ 1;      // write buffers
    // lo-plane read base for this wave's hc (advance by kc*8*512 per kc)
    const size_t loR = (((size_t)pc * BB + b) * 64 + hc) * 512 + l * 8;

    for (int rc = 0; rc < 8; ++rc) {
      // c load for this chunk (latency hidden under phase A MFMAs)
      F4 c4[2];
      const size_t coff = (((size_t)b * 8 + rc) * 512 + tid) * 8;
      c4[0].v = *(const float4*)&cG[coff];
      c4[1].v = *(const float4*)&cG[coff + 4];

      // ---- phase A: two 16x16 tiles (rt=0,1) per wave ----
      f32x4 accA[2];
      accA[0] = (f32x4){0.f, 0.f, 0.f, 0.f};
      accA[1] = (f32x4){0.f, 0.f, 0.f, 0.f};
      const size_t abase = (((size_t)b * 16 + 2 * rc) * 8) * 512 + l * 8;
      for (int kc = 0; kc < 8; ++kc) {
        const half8 bH = *(const half8*)&hFH[pc][(kc * 8 + hc) * 512 + l * 8];
        const half8 bL = *(const half8*)&hGL[loR + (size_t)kc * 4096];
        const half8 aH0 = *(const half8*)&AfH[abase + (size_t)kc * 512];
        const half8 aL0 = *(const half8*)&AfL[abase + (size_t)kc * 512];
        const half8 aH1 = *(const half8*)&AfH[abase + 4096 + (size_t)kc * 512];
        const half8 aL1 = *(const half8*)&AfL[abase + 4096 + (size_t)kc * 512];
        accA[0] = __builtin_amdgcn_mfma_f32_16x16x32_f16(aL0, bH, accA[0], 0, 0, 0);
        accA[0] = __builtin_amdgcn_mfma_f32_16x16x32_f16(aH0, bL, accA[0], 0, 0, 0);
        accA[0] = __builtin_amdgcn_mfma_f32_16x16x32_f16(aH0, bH, accA[0], 0, 0, 0);
        accA[1] = __builtin_amdgcn_mfma_f32_16x16x32_f16(aL1, bH, accA[1], 0, 0, 0);
        accA[1] = __builtin_amdgcn_mfma_f32_16x16x32_f16(aH1, bL, accA[1], 0, 0, 0);
        accA[1] = __builtin_amdgcn_mfma_f32_16x16x32_f16(aH1, bH, accA[1], 0, 0, 0);
      }
      // stage Ax[t] chunk -> region cols 128..143 (all 512 threads)
      {
        const int r = tid >> 4, f = tid & 15;
        region[r * 164 + 128 + f] =
            Ax[(((size_t)(b * TT + t)) * NN + rc * 32 + r) * FF + f];
      }
      // C-write Ah (col=lane&15, row=quad*4+reg)
#pragma unroll
      for (int rt = 0; rt < 2; ++rt)
#pragma unroll
        for (int r = 0; r < 4; ++r)
          region[(rt * 16 + quad * 4 + r) * 164 + hc * 16 + lo16] = accA[rt][r];
      __syncthreads();  // B1: Ah + Ax staged

      // ---- phase B: gate tiles (g*8+hc), both row tiles ----
      f32x4 acc[2][4];
#pragma unroll
      for (int rt = 0; rt < 2; ++rt)
#pragma unroll
        for (int g = 0; g < 4; ++g) acc[rt][g] = (f32x4){0.f, 0.f, 0.f, 0.f};

      for (int kc = 0; kc < 5; ++kc) {
        half8 pH[2], pL[2];
#pragma unroll
        for (int rt = 0; rt < 2; ++rt) {
          const float* src = &region[(rt * 16 + lo16) * 164 + kc * 32 + quad * 8];
          const float4 v0 = *(const float4*)src;
          const float4 v1 = *(const float4*)(src + 4);
          float av[8] = {v0.x, v0.y, v0.z, v0.w, v1.x, v1.y, v1.z, v1.w};
          split8(av, pH[rt], pL[rt]);
        }
#pragma unroll
        for (int g = 0; g < 4; ++g) {
          const size_t woff = ((size_t)(kc * 32 + g * 8 + hc)) * 512 + l * 8;
          const half8 wH = *(const half8*)&WfH[woff];
          const half8 wL = *(const half8*)&WfL[woff];
#pragma unroll
          for (int rt = 0; rt < 2; ++rt) {
            acc[rt][g] = __builtin_amdgcn_mfma_f32_16x16x32_f16(pL[rt], wH, acc[rt][g], 0, 0, 0);
            acc[rt][g] = __builtin_amdgcn_mfma_f32_16x16x32_f16(pH[rt], wL, acc[rt][g], 0, 0, 0);
            acc[rt][g] = __builtin_amdgcn_mfma_f32_16x16x32_f16(pH[rt], wH, acc[rt][g], 0, 0, 0);
          }
        }
      }

      // ---- LSTM pointwise in registers; h(t+1) straight to frag stores ----
#pragma unroll
      for (int rt = 0; rt < 2; ++rt) {
        half4 h4, l4;
        F4 cn;
#pragma unroll
        for (int r = 0; r < 4; ++r) {
          const float iv = sigf(acc[rt][0][r] + bi[0]);
          const float fv = sigf(acc[rt][1][r] + bi[1]);
          const float gv = tanhfast(acc[rt][2][r] + bi[2]);
          const float ov = sigf(acc[rt][3][r] + bi[3]);
          const float cnew = fv * c4[rt].a[r] + iv * gv;
          cn.a[r] = cnew;
          const float hv = ov * tanhfast(cnew);
          const _Float16 hh = (_Float16)hv;
          h4[r] = hh;
          l4[r] = (_Float16)(hv - (float)hh);
          if (t == TT - 1 && rc == 0) {
            const int node = rt * 16 + quad * 4 + r;
            h32[((size_t)b * 32 + node) * HH + hc * 16 + lo16] = hv;
          }
        }
        *(float4*)&cG[coff + rt * 4] = cn.v;
        if (t != TT - 1) {
          const int lp = rt ? lp1 : lp0;
          // hi -> LDS next buffer (disjoint from read buffer pc)
          *(half4*)&hFH[pn][(rc * 8 + hc) * 512 + lp * 8 + j0] = h4;
          // lo -> global next buffer
          *(half4*)&hGL[(((size_t)pn * BB + b) * 64 + rc * 8 + hc) * 512 + lp * 8 + j0] = l4;
        }
      }
      __syncthreads();  // B2: region reads done; chunk-7 B2 also fences
                        // hi/lo next-buffer writes for next step (vmcnt drain)
    }
  }
}

// ---------------------------------------------------------------------------
// Tail: GRU over t + fc5/fc2/fc3/fc4. grid = B, 384 threads.
// h32 layout: [b][node 0..31][128] (only node tile 0 is stored; tsi=5 < 32).
// ---------------------------------------------------------------------------
__global__ __launch_bounds__(384) void k_tail(
    const float* __restrict__ x, const float* __restrict__ h32,
    const int* __restrict__ tsi_p, const float* __restrict__ gruWih,
    const float* __restrict__ gruWhh, const float* __restrict__ gru_bih,
    const float* __restrict__ gru_bhh, const float* __restrict__ fc2W,
    const float* __restrict__ fc2b, const float* __restrict__ fc3W,
    const float* __restrict__ fc3b, const float* __restrict__ fc4W,
    const float* __restrict__ fc4b, const float* __restrict__ fc5W,
    const float* __restrict__ fc5b, float* __restrict__ out) {
  const int b = blockIdx.x;
  const int m = threadIdx.x;
  const int tsi = tsi_p[0];

  __shared__ float h_s[HH];
  __shared__ float xts[TT * FF];
  __shared__ float sum_s[384];
  __shared__ float gh_s[384];
  __shared__ float hc_s[2 * HH];
  __shared__ float xr_s[HH];
  __shared__ float f2_s[HH];
  __shared__ float f3_s[64];

  float4 whh[32];
#pragma unroll
  for (int q = 0; q < 32; ++q) whh[q] = *(const float4*)&gruWhh[(size_t)m * HH + q * 4];
  float4 wih[4];
#pragma unroll
  for (int q = 0; q < 4; ++q) wih[q] = *(const float4*)&gruWih[(size_t)m * FF + q * 4];
  const float bih_r = gru_bih[m];
  const float bhh_r = gru_bhh[m];

  {
    const int t = m >> 4, f = m & 15;
    xts[m] = x[(((size_t)b * TT + t) * NN + tsi) * FF + f];
  }
  if (m < HH) h_s[m] = 0.f;
  __syncthreads();

  for (int t = 0; t < TT; ++t) {
    float gi = bih_r;
#pragma unroll
    for (int q = 0; q < 4; ++q) {
      const float4 xv = *(const float4*)&xts[t * FF + q * 4];
      gi += wih[q].x * xv.x + wih[q].y * xv.y + wih[q].z * xv.z + wih[q].w * xv.w;
    }
    float gh = bhh_r;
#pragma unroll
    for (int q = 0; q < 32; ++q) {
      const float4 hv = *(const float4*)&h_s[q * 4];
      gh += whh[q].x * hv.x + whh[q].y * hv.y + whh[q].z * hv.z + whh[q].w * hv.w;
    }
    sum_s[m] = gi + gh;
    gh_s[m] = gh;
    __syncthreads();
    float hnew = 0.f;
    if (m < HH) {
      const float r = sigf(sum_s[m]);
      const float z = sigf(sum_s[HH + m]);
      const float ghn = gh_s[2 * HH + m];
      const float nn = tanhfast(sum_s[2 * HH + m] - ghn + r * ghn);
      hnew = (1.f - z) * nn + z * h_s[m];
    }
    __syncthreads();
    if (m < HH) h_s[m] = hnew;
    __syncthreads();
  }

  if (m < HH) {
    hc_s[m] = h_s[m];
    xr_s[m] = fmaxf(h32[((size_t)b * 32 + tsi) * HH + m], 0.f);
  }
  __syncthreads();
  if (m < HH) {
    float v = fc5b[m];
    const float* wr = fc5W + (size_t)m * HH;
#pragma unroll 8
    for (int k = 0; k < HH; k += 4) {
      const float4 wv = *(const float4*)(wr + k);
      v += xr_s[k] * wv.x + xr_s[k + 1] * wv.y + xr_s[k + 2] * wv.z + xr_s[k + 3] * wv.w;
    }
    hc_s[HH + m] = v;
  }
  __syncthreads();
  if (m < HH) {
    float v = fc2b[m];
    const float* wr = fc2W + (size_t)m * 2 * HH;
#pragma unroll 8
    for (int k = 0; k < 2 * HH; k += 4) {
      const float4 wv = *(const float4*)(wr + k);
      v += hc_s[k] * wv.x + hc_s[k + 1] * wv.y + hc_s[k + 2] * wv.z + hc_s[k + 3] * wv.w;
    }
    f2_s[m] = fmaxf(v, 0.f);
  }
  __syncthreads();
  if (m < 64) {
    float v = fc3b[m];
    const float* wr = fc3W + (size_t)m * HH;
#pragma unroll 8
    for (int k = 0; k < HH; k += 4) {
      const float4 wv = *(const float4*)(wr + k);
      v += f2_s[k] * wv.x + f2_s[k + 1] * wv.y + f2_s[k + 2] * wv.z + f2_s[k + 3] * wv.w;
    }
    f3_s[m] = fmaxf(v, 0.f);
  }
  __syncthreads();
  if (m < 24) {
    float v = fc4b[m];
    const float* wr = fc4W + (size_t)m * 64;
#pragma unroll
    for (int k = 0; k < 64; k += 4) {
      const float4 wv = *(const float4*)(wr + k);
      v += f3_s[k] * wv.x + f3_s[k + 1] * wv.y + f3_s[k + 2] * wv.z + f3_s[k + 3] * wv.w;
    }
    out[b * 24 + m] = v;
  }
}

// ---------------------------------------------------------------------------
extern "C" void kernel_launch(void* const* d_in, const int* in_sizes, int n_in,
                              void* d_out, int out_size, void* d_ws, size_t ws_size,
                              hipStream_t stream) {
  const float* x = (const float*)d_in[0];
  const float* adj = (const float*)d_in[1];
  const int* tsi = (const int*)d_in[2];
  const float* gcnW = (const float*)d_in[3];
  const float* gcnb = (const float*)d_in[4];
  const float* gruWih = (const float*)d_in[5];
  const float* gruWhh = (const float*)d_in[6];
  const float* gru_bih = (const float*)d_in[7];
  const float* gru_bhh = (const float*)d_in[8];
  const float* fc2W = (const float*)d_in[9];
  const float* fc2b = (const float*)d_in[10];
  const float* fc3W = (const float*)d_in[11];
  const float* fc3b = (const float*)d_in[12];
  const float* fc4W = (const float*)d_in[13];
  const float* fc4b = (const float*)d_in[14];
  const float* fc5W = (const float*)d_in[15];
  const float* fc5b = (const float*)d_in[16];
  float* out = (float*)d_out;

  // ws layout (elements)
  float* Ax = (float*)d_ws;                           // 32*24*256*16 = 3,145,728 f
  float* h32 = Ax + 3145728;                          // 32*32*128   =   131,072 f
  _Float16* AfH = (_Float16*)(h32 + 131072);          // 32*16*8*512 = 2,097,152 h
  _Float16* AfL = AfH + 2097152;                      // 2,097,152 h
  _Float16* WfH = AfL + 2097152;                      // 5*32*512    =    81,920 h
  _Float16* WfL = WfH + 81920;                        // 81,920 h
  _Float16* hGL = WfL + 81920;                        // 2*32*64*512 = 2,097,152 h (lo dbuf)
  float* cG = (float*)(hGL + 2097152);                // 32*8*512*8  = 1,048,576 f (cell)

  // zero hGL (h(-1)-lo = 0; parity-1 harmless) + cG (c(-1)=0): contiguous 8 MB
  hipMemsetAsync(hGL, 0, 2097152 * 2 + 1048576 * 4, stream);

  k0_wswz<<<dim3(160), 64, 0, stream>>>(gcnW, WfH, WfL);
  k0_aswz<<<dim3(128, BB), 64, 0, stream>>>(adj, AfH, AfL);
  k1_ax<<<dim3(BB * TT), 256, 0, stream>>>(adj, x, Ax);

  // one block per b; entire 24-step scan runs in-block (no cross-block sync)
  k2_b<<<dim3(BB), 512, 0, stream>>>(AfH, AfL, WfH, WfL, Ax, gcnb, hGL, cG, h32);

  k_tail<<<dim3(BB), 384, 0, stream>>>(x, h32, tsi, gruWih, gruWhh, gru_bih, gru_bhh, fc2W,
                                       fc2b, fc3W, fc3b, fc4W, fc4b, fc5W, fc5b, out);
}